// Round 14
// baseline (247.976 us; speedup 1.0000x reference)
//
#include <hip/hip_runtime.h>
#include <hip/hip_bf16.h>

typedef __hip_bfloat16 bf16;

// flags[0] = 1 if floats are f32 (else bf16); flags[1] = 1 if ints are int64 (else int32)
static __device__ __forceinline__ float loadF(const void* p, long long i, int f32){
  return f32 ? ((const float*)p)[i] : __bfloat162float(((const bf16*)p)[i]);
}
static __device__ __forceinline__ int loadI(const void* p, long long i, int i64){
  return i64 ? (int)((const long long*)p)[i] : ((const int*)p)[i];
}
// round-to-nearest-even float -> bf16 bits (finite inputs)
static __device__ __forceinline__ unsigned short f2bf(float f){
  unsigned u = __float_as_uint(f);
  return (unsigned short)((u + 0x7FFFu + ((u>>16)&1u)) >> 16);
}
static __device__ __forceinline__ float bf2f(unsigned v){
  return __uint_as_float(v<<16);
}

#define CAP 4096        // log entries per bucket (avg ~1023)
#define LB_EDGES 8192   // edges per logbuild block (98 blocks; 32KB stash)

// ---------------- fused pre-pass (512 threads, 40KB LDS -> 4 blocks/CU) ----------------
// blocks [0, nLog): packed edge log build; blocks [nLog, ...): y = x @ W1, 64-row tiles.
__global__ __launch_bounds__(512) void k_pre(const void* __restrict__ ei, int E, int N,
                                             int* __restrict__ flags,
                                             int* __restrict__ gcursor,
                                             unsigned int* __restrict__ log, int nbuckets,
                                             const void* __restrict__ x, const void* __restrict__ W,
                                             unsigned short* __restrict__ y, int nLog){
  __shared__ unsigned int smem[10240];   // 40960 B exactly (log: 32K stash + 8K hists; gemm: 33KB)
  __shared__ int sflag[2];
  int t = threadIdx.x;
  // ---- per-block dtype sniff (L2-broadcast reads, ~2KB shared by all blocks) ----
  if(t == 0){ sflag[0] = 0; sflag[1] = 0; }
  __syncthreads();
  {
    const unsigned int* xw  = (const unsigned int*)x;
    const unsigned int* eiw = (const unsigned int*)ei;
    if(t < 256){
      unsigned w = xw[t];
      int e = (int)((w>>7)&0xFFu);
      if(e>=110 && e<=135) atomicAdd(&sflag[0], 1);      // bf16-pair exponent signature
    } else {
      int i = t - 256;
      if(eiw[2*i+1] != 0u) atomicAdd(&sflag[1], 1);      // int64 high words
    }
  }
  __syncthreads();
  int f32 = (sflag[0] < 128) ? 1 : 0;
  int i64 = (sflag[1] < 128) ? 1 : 0;
  if(blockIdx.x == 0 && t == 0){ flags[0] = f32; flags[1] = i64; }  // for later kernels
  if((int)blockIdx.x < nLog){
    // ---- logbuild role: packed (dst<<16)|src, grouped by dst>>6 ----
    unsigned int* stash = smem;                       // [0, 8192): 32 KB
    int* hcnt  = (int*)(smem + LB_EDGES);             // [8192, 9216): 4 KB
    int* hbase = (int*)(smem + LB_EDGES + 1024);      // [9216, 10240): 4 KB
    for(int b=t; b<nbuckets; b+=512) hcnt[b] = 0;
    __syncthreads();
    long long e0 = (long long)blockIdx.x*LB_EDGES;
    int cnt = (int)(((long long)E - e0) < LB_EDGES ? ((long long)E - e0) : LB_EDGES);
    for(int k=t; k<cnt; k+=512){
      long long e = e0 + k;
      int s = loadI(ei, e, i64);                 s = min(max(s,0), N-1);
      int d = loadI(ei, (long long)E + e, i64);  d = min(max(d,0), N-1);
      unsigned p = (((unsigned)d)<<16) | (unsigned)s;   // requires N <= 65536
      stash[k] = p;
      atomicAdd(&hcnt[d>>6], 1);
    }
    __syncthreads();
    for(int b=t; b<nbuckets; b+=512){
      int c = hcnt[b];
      hbase[b] = (c>0) ? atomicAdd(&gcursor[b], c) : 0;
      hcnt[b] = 0;
    }
    __syncthreads();
    for(int k=t; k<cnt; k+=512){
      unsigned p = stash[k];
      int b = (int)(p>>22);                      // dst>>6
      int pos = hbase[b] + atomicAdd(&hcnt[b], 1);
      if(pos < CAP) log[(long long)b*CAP + pos] = p;
    }
  } else {
    // ---- gemm role: y = x @ W1, 64 rows x 64 cols per block, 2 rows x 4 cols/thread ----
    float* Ws = (float*)smem;                    // [0, 4096): 16 KB
    float* xs = (float*)(smem + 4096);           // 64*65 floats = 16640 B
    int row0 = ((int)blockIdx.x - nLog)*64;
    if(f32){
      const float4* W4 = (const float4*)W;
      for(int i=t;i<1024;i+=512){
        float4 v = W4[i];
        Ws[i*4]=v.x; Ws[i*4+1]=v.y; Ws[i*4+2]=v.z; Ws[i*4+3]=v.w;
      }
      const float4* X4 = (const float4*)x;
      for(int i=t;i<1024;i+=512){
        int r = i>>4, c4 = i&15;
        int gr = row0 + r;
        float4 v = {0.f,0.f,0.f,0.f};
        if(gr<N) v = X4[(long long)gr*16 + c4];
        float* xd = &xs[r*65 + c4*4];
        xd[0]=v.x; xd[1]=v.y; xd[2]=v.z; xd[3]=v.w;
      }
    } else {
      for(int i=t;i<4096;i+=512) Ws[i] = loadF(W, i, 0);
      const unsigned int* X32 = (const unsigned int*)x;
      for(int i=t;i<2048;i+=512){
        int r = i>>5, kd = i&31;
        int gr = row0 + r;
        unsigned v = (gr<N) ? X32[(long long)gr*32 + kd] : 0u;
        xs[r*65 + 2*kd    ] = bf2f(v & 0xFFFFu);
        xs[r*65 + 2*kd + 1] = bf2f(v >> 16);
      }
    }
    __syncthreads();
    int cg = t&15, rg = t>>4;                    // rg in [0,32): 2 rows each
    int col_g = cg*4, row_g = rg*2;
    float acc[2][4];
    #pragma unroll
    for(int r=0;r<2;r++){ acc[r][0]=0.f; acc[r][1]=0.f; acc[r][2]=0.f; acc[r][3]=0.f; }
    for(int k=0;k<64;k++){
      float4 w = *(const float4*)&Ws[k*64 + col_g];
      float xr[2];
      #pragma unroll
      for(int r=0;r<2;r++) xr[r] = xs[(row_g+r)*65 + k];
      #pragma unroll
      for(int r=0;r<2;r++){
        acc[r][0] += xr[r]*w.x; acc[r][1] += xr[r]*w.y;
        acc[r][2] += xr[r]*w.z; acc[r][3] += xr[r]*w.w;
      }
    }
    #pragma unroll
    for(int r=0;r<2;r++){
      int gr = row0 + row_g + r;
      if(gr<N){
        ushort4 st;
        st.x = f2bf(acc[r][0]); st.y = f2bf(acc[r][1]);
        st.z = f2bf(acc[r][2]); st.w = f2bf(acc[r][3]);
        *(ushort4*)&y[(long long)gr*64 + col_g] = st;
      }
    }
  }
}

// ---------------- per-bucket counting sort + dinv (512 threads) ----------------
__global__ __launch_bounds__(512) void k_bsort(const unsigned int* __restrict__ log,
                                               const int* __restrict__ gcursor,
                                               unsigned short* __restrict__ csr,
                                               int* __restrict__ beg, int* __restrict__ endv,
                                               float* __restrict__ dinv, int N){
  __shared__ int hist[64];
  __shared__ int cur[64];
  int b = blockIdx.x, t = threadIdx.x;
  if(t < 64) hist[t] = 0;
  __syncthreads();
  int n = min(gcursor[b], CAP);
  const unsigned int* L = log + (long long)b*CAP;
  for(int j=t; j<n; j+=512) atomicAdd(&hist[(L[j]>>16)&63], 1);
  __syncthreads();
  if(t < 64){                                   // wave 0: exclusive scan over 64 bins
    int v = hist[t];
    int inc = v;
    #pragma unroll
    for(int o=1; o<64; o<<=1){
      int u = __shfl_up(inc, o);
      if(t >= o) inc += u;
    }
    int excl = inc - v;
    cur[t] = excl;
    int node = b*64 + t;
    if(node < N){
      int base = b*CAP + excl;
      beg[node]  = base;
      endv[node] = base + v;
      dinv[node] = rsqrtf((float)(v + 1));      // +1 = self loop
    }
  }
  __syncthreads();
  unsigned short* C = csr + (long long)b*CAP;
  for(int j=t; j<n; j+=512){
    unsigned p = L[j];
    int l = (int)((p>>16)&63u);
    int pos = atomicAdd(&cur[l], 1);
    C[pos] = (unsigned short)(p & 0xFFFFu);
  }
}

// ---------------- AGG: wave per node, uint4 row-segment gather ----------------
// lane = (eg = lane>>3 edge slot, q = lane&7 feat segment); one vector instr = 8 rows.
// Self-row + dinv issued BEFORE the gather loop so their latency hides under it.
// mode=1: input is y (unscaled) -> rows scaled by dinv[s], self by dv;
//         out = bf16( relu( dv*(sum dinv_s*y_s + dv*y_d) + bias ) * dv )   [pre-scaled for next hop]
// mode=0: input pre-scaled -> out = bf16( dv*(sum g_s + g_d) )
__global__ __launch_bounds__(256) void k_agg(const unsigned short* __restrict__ g,
                                             const unsigned short* __restrict__ csr,
                                             const int* __restrict__ beg, const int* __restrict__ endv,
                                             const float* __restrict__ dinv,
                                             const void* __restrict__ bias, const int* __restrict__ flags,
                                             int mode,
                                             uint4* __restrict__ out128, int N){
  int node = blockIdx.x*4 + (threadIdx.x>>6);
  int lane = threadIdx.x&63;
  if(node >= N) return;
  int q = lane&7, eg = lane>>3;
  const uint4* G128 = (const uint4*)g;          // row = 8 uint4 (64 bf16)
  // issue self row + dinv EARLY — overlaps the whole gather phase
  uint4 sv = {0u,0u,0u,0u};
  float dv = 0.f;
  if(eg == 0){
    sv = G128[(long long)node*8 + q];
    dv = dinv[node];
  }
  int j = beg[node], e = endv[node];
  float a0=0.f,a1=0.f,a2=0.f,a3=0.f,a4=0.f,a5=0.f,a6=0.f,a7=0.f;
  if(mode){                                     // gather with per-edge dinv[s] scale
    for(; j+16<=e; j+=16){
      int sA = csr[j + eg];
      int sB = csr[j + 8 + eg];
      float dA = dinv[sA], dB = dinv[sB];
      uint4 vA = G128[(long long)sA*8 + q];
      uint4 vB = G128[(long long)sB*8 + q];
      a0 += dA*bf2f(vA.x & 0xFFFFu); a1 += dA*bf2f(vA.x >> 16);
      a2 += dA*bf2f(vA.y & 0xFFFFu); a3 += dA*bf2f(vA.y >> 16);
      a4 += dA*bf2f(vA.z & 0xFFFFu); a5 += dA*bf2f(vA.z >> 16);
      a6 += dA*bf2f(vA.w & 0xFFFFu); a7 += dA*bf2f(vA.w >> 16);
      a0 += dB*bf2f(vB.x & 0xFFFFu); a1 += dB*bf2f(vB.x >> 16);
      a2 += dB*bf2f(vB.y & 0xFFFFu); a3 += dB*bf2f(vB.y >> 16);
      a4 += dB*bf2f(vB.z & 0xFFFFu); a5 += dB*bf2f(vB.z >> 16);
      a6 += dB*bf2f(vB.w & 0xFFFFu); a7 += dB*bf2f(vB.w >> 16);
    }
    for(; j+8<=e; j+=8){
      int s = csr[j + eg];
      float d = dinv[s];
      uint4 v = G128[(long long)s*8 + q];
      a0 += d*bf2f(v.x & 0xFFFFu); a1 += d*bf2f(v.x >> 16);
      a2 += d*bf2f(v.y & 0xFFFFu); a3 += d*bf2f(v.y >> 16);
      a4 += d*bf2f(v.z & 0xFFFFu); a5 += d*bf2f(v.z >> 16);
      a6 += d*bf2f(v.w & 0xFFFFu); a7 += d*bf2f(v.w >> 16);
    }
    if(j + eg < e){
      int s = csr[j + eg];
      float d = dinv[s];
      uint4 v = G128[(long long)s*8 + q];
      a0 += d*bf2f(v.x & 0xFFFFu); a1 += d*bf2f(v.x >> 16);
      a2 += d*bf2f(v.y & 0xFFFFu); a3 += d*bf2f(v.y >> 16);
      a4 += d*bf2f(v.z & 0xFFFFu); a5 += d*bf2f(v.z >> 16);
      a6 += d*bf2f(v.w & 0xFFFFu); a7 += d*bf2f(v.w >> 16);
    }
  } else {
    for(; j+16<=e; j+=16){
      int sA = csr[j + eg];
      int sB = csr[j + 8 + eg];
      uint4 vA = G128[(long long)sA*8 + q];
      uint4 vB = G128[(long long)sB*8 + q];
      a0 += bf2f(vA.x & 0xFFFFu); a1 += bf2f(vA.x >> 16);
      a2 += bf2f(vA.y & 0xFFFFu); a3 += bf2f(vA.y >> 16);
      a4 += bf2f(vA.z & 0xFFFFu); a5 += bf2f(vA.z >> 16);
      a6 += bf2f(vA.w & 0xFFFFu); a7 += bf2f(vA.w >> 16);
      a0 += bf2f(vB.x & 0xFFFFu); a1 += bf2f(vB.x >> 16);
      a2 += bf2f(vB.y & 0xFFFFu); a3 += bf2f(vB.y >> 16);
      a4 += bf2f(vB.z & 0xFFFFu); a5 += bf2f(vB.z >> 16);
      a6 += bf2f(vB.w & 0xFFFFu); a7 += bf2f(vB.w >> 16);
    }
    for(; j+8<=e; j+=8){
      int s = csr[j + eg];
      uint4 v = G128[(long long)s*8 + q];
      a0 += bf2f(v.x & 0xFFFFu); a1 += bf2f(v.x >> 16);
      a2 += bf2f(v.y & 0xFFFFu); a3 += bf2f(v.y >> 16);
      a4 += bf2f(v.z & 0xFFFFu); a5 += bf2f(v.z >> 16);
      a6 += bf2f(v.w & 0xFFFFu); a7 += bf2f(v.w >> 16);
    }
    if(j + eg < e){
      int s = csr[j + eg];
      uint4 v = G128[(long long)s*8 + q];
      a0 += bf2f(v.x & 0xFFFFu); a1 += bf2f(v.x >> 16);
      a2 += bf2f(v.y & 0xFFFFu); a3 += bf2f(v.y >> 16);
      a4 += bf2f(v.z & 0xFFFFu); a5 += bf2f(v.z >> 16);
      a6 += bf2f(v.w & 0xFFFFu); a7 += bf2f(v.w >> 16);
    }
  }
  #pragma unroll
  for(int m=8; m<64; m<<=1){                    // combine 8 edge slots
    a0 += __shfl_xor(a0, m, 64); a1 += __shfl_xor(a1, m, 64);
    a2 += __shfl_xor(a2, m, 64); a3 += __shfl_xor(a3, m, 64);
    a4 += __shfl_xor(a4, m, 64); a5 += __shfl_xor(a5, m, 64);
    a6 += __shfl_xor(a6, m, 64); a7 += __shfl_xor(a7, m, 64);
  }
  if(eg == 0){
    float selfs = mode ? dv : 1.f;              // mode1: self term is dv*y_d
    float f0 = (a0 + selfs*bf2f(sv.x & 0xFFFFu)) * dv;
    float f1 = (a1 + selfs*bf2f(sv.x >> 16)) * dv;
    float f2 = (a2 + selfs*bf2f(sv.y & 0xFFFFu)) * dv;
    float f3 = (a3 + selfs*bf2f(sv.y >> 16)) * dv;
    float f4 = (a4 + selfs*bf2f(sv.z & 0xFFFFu)) * dv;
    float f5 = (a5 + selfs*bf2f(sv.z >> 16)) * dv;
    float f6 = (a6 + selfs*bf2f(sv.w & 0xFFFFu)) * dv;
    float f7 = (a7 + selfs*bf2f(sv.w >> 16)) * dv;
    if(mode){                                   // layer-1 epilogue: relu(S+b1)*dinv
      int f32 = flags[0];
      f0 = fmaxf(f0 + loadF(bias, q*8+0, f32), 0.f) * dv;
      f1 = fmaxf(f1 + loadF(bias, q*8+1, f32), 0.f) * dv;
      f2 = fmaxf(f2 + loadF(bias, q*8+2, f32), 0.f) * dv;
      f3 = fmaxf(f3 + loadF(bias, q*8+3, f32), 0.f) * dv;
      f4 = fmaxf(f4 + loadF(bias, q*8+4, f32), 0.f) * dv;
      f5 = fmaxf(f5 + loadF(bias, q*8+5, f32), 0.f) * dv;
      f6 = fmaxf(f6 + loadF(bias, q*8+6, f32), 0.f) * dv;
      f7 = fmaxf(f7 + loadF(bias, q*8+7, f32), 0.f) * dv;
    }
    uint4 o;
    o.x = (unsigned)f2bf(f0) | ((unsigned)f2bf(f1) << 16);
    o.y = (unsigned)f2bf(f2) | ((unsigned)f2bf(f3) << 16);
    o.z = (unsigned)f2bf(f4) | ((unsigned)f2bf(f5) << 16);
    o.w = (unsigned)f2bf(f6) | ((unsigned)f2bf(f7) << 16);
    out128[(long long)node*8 + q] = o;
  }
}

// ---------------- fused GEMM2 + relu + fcW-dot + mean-pool + (last block) final ----------------
// 512 threads (8 waves): thread covers 4 rows x 8 cols of the 128x128 tile.
static __device__ __forceinline__ int lower_bound_batch(const void* batch, int N, int key, int i64){
  int lo = 0, hi = N;
  while(lo < hi){ int mid = (lo+hi)>>1; if(loadI(batch, mid, i64) < key) lo = mid+1; else hi = mid; }
  return lo;
}

__global__ __launch_bounds__(512) void k_gemm2pool(const unsigned int* __restrict__ A32, const void* __restrict__ W,
                                                   const void* __restrict__ b, const void* __restrict__ fcW,
                                                   const void* __restrict__ batch, const int* __restrict__ flags,
                                                   float* __restrict__ S, int* __restrict__ done,
                                                   const void* __restrict__ fcb, void* __restrict__ out,
                                                   int N, int G, int NOUT){
  __shared__ float Ws[64*128];     // 32 KB
  __shared__ float xs[128*65];     // 32.5 KB
  __shared__ float Sloc[128*4];
  __shared__ int gid[128];
  __shared__ int lastBlk;
  int f32 = flags[0], i64 = flags[1];
  int tid = threadIdx.x;
  int row0 = blockIdx.x*128;
  if(f32){
    const float4* W4 = (const float4*)W;
    for(int i=tid;i<2048;i+=512){
      float4 v = W4[i];
      Ws[i*4]=v.x; Ws[i*4+1]=v.y; Ws[i*4+2]=v.z; Ws[i*4+3]=v.w;
    }
  } else {
    for(int i=tid;i<8192;i+=512) Ws[i] = loadF(W, i, 0);
  }
  for(int i=tid;i<4096;i+=512){                 // 4096 dwords = 128 rows x 32 dwords
    int r = i>>5, kd = i&31;
    int gr = row0 + r;
    unsigned v = (gr<N) ? A32[(long long)gr*32 + kd] : 0u;
    xs[r*65 + 2*kd    ] = bf2f(v & 0xFFFFu);
    xs[r*65 + 2*kd + 1] = bf2f(v >> 16);
  }
  if(tid < 128){
    int node = row0 + tid;
    gid[tid] = (node < N) ? loadI(batch, node, i64) : 0;
  }
  if(tid < 512) Sloc[tid] = 0.f;
  __syncthreads();
  int cg = tid&15, rg = tid>>4;                 // rg in [0,32): 4 rows each
  int c0 = cg*4, c1 = 64 + cg*4, row_g = rg*4;
  float acc[4][8];
  #pragma unroll
  for(int r=0;r<4;r++)
    #pragma unroll
    for(int c=0;c<8;c++) acc[r][c]=0.f;
  for(int k=0;k<64;k++){
    float4 w0 = *(const float4*)&Ws[k*128 + c0];
    float4 w1 = *(const float4*)&Ws[k*128 + c1];
    float xr[4];
    #pragma unroll
    for(int r=0;r<4;r++) xr[r] = xs[(row_g+r)*65 + k];
    #pragma unroll
    for(int r=0;r<4;r++){
      acc[r][0] += xr[r]*w0.x; acc[r][1] += xr[r]*w0.y;
      acc[r][2] += xr[r]*w0.z; acc[r][3] += xr[r]*w0.w;
      acc[r][4] += xr[r]*w1.x; acc[r][5] += xr[r]*w1.y;
      acc[r][6] += xr[r]*w1.z; acc[r][7] += xr[r]*w1.w;
    }
  }
  // bias + relu in registers
  #pragma unroll
  for(int c=0;c<8;c++){
    int col = (c<4) ? (c0+c) : (c1+c-4);
    float bb = loadF(b, col, f32);
    #pragma unroll
    for(int r=0;r<4;r++){ float z = acc[r][c]+bb; acc[r][c] = z>0.f?z:0.f; }
  }
  // fcW dot + pooled partial sums
  int nv = N - row0; nv = nv < 128 ? nv : 128;
  if(nv > 0){
    int gmin = gid[0], gmax = gid[nv-1];
    bool ldsOK = (NOUT <= 4) && (gmax - gmin < 128);
    for(int o=0;o<NOUT;o++){
      float fw[8];
      #pragma unroll
      for(int c=0;c<8;c++){
        int col = (c<4) ? (c0+c) : (c1+c-4);
        fw[c] = loadF(fcW, (long long)col*NOUT + o, f32);
      }
      #pragma unroll
      for(int r=0;r<4;r++){
        float z = acc[r][0]*fw[0] + acc[r][1]*fw[1] + acc[r][2]*fw[2] + acc[r][3]*fw[3]
                + acc[r][4]*fw[4] + acc[r][5]*fw[5] + acc[r][6]*fw[6] + acc[r][7]*fw[7];
        #pragma unroll
        for(int m=1;m<16;m<<=1) z += __shfl_xor(z, m, 64);
        int nl = row_g + r;
        if(cg==0 && nl < nv){
          int gg = gid[nl];
          if(ldsOK) atomicAdd(&Sloc[(gg-gmin)*NOUT + o], z);
          else      atomicAdd(&S[(long long)gg*NOUT + o], z);
        }
      }
    }
    if(ldsOK){
      __syncthreads();
      int nbin = (gmax - gmin + 1)*NOUT;
      for(int i=tid; i<nbin; i+=512){
        float v = Sloc[i];
        if(v != 0.f){
          int bin = i / NOUT, o = i - bin*NOUT;
          atomicAdd(&S[(long long)(gmin+bin)*NOUT + o], v);
        }
      }
    }
  }
  // last-block final: out[g,o] = S[g,o]/count_g + fcb[o].
  // All S updates are DEVICE-SCOPE atomicAdds (performed at the coherence point),
  // so no cache writeback is needed — only completion before done++ is observed.
  asm volatile("s_waitcnt vmcnt(0)" ::: "memory");
  if(tid==0) lastBlk = (atomicAdd(done, 1) == (int)gridDim.x - 1) ? 1 : 0;
  __syncthreads();
  if(lastBlk){
    for(int g2=tid; g2<G; g2+=512){
      int c = lower_bound_batch(batch, N, g2+1, i64) - lower_bound_batch(batch, N, g2, i64);
      float inv = 1.f / (float)(c > 0 ? c : 1);
      for(int o=0;o<NOUT;o++){
        float sv = atomicAdd(&S[(long long)g2*NOUT + o], 0.f);   // coherent device-scope read
        float r = sv*inv + loadF(fcb, o, f32);
        if(f32) ((float*)out)[g2*NOUT+o] = r;
        else    ((unsigned short*)out)[g2*NOUT+o] = f2bf(r);
      }
    }
  }
}

extern "C" void kernel_launch(void* const* d_in, const int* in_sizes, int n_in,
                              void* d_out, int out_size, void* d_ws, size_t ws_size,
                              hipStream_t stream) {
  const void* x    = d_in[0];
  const void* ei   = d_in[1];
  const void* batch= d_in[2];
  const void* W1   = d_in[3];
  const void* b1   = d_in[4];
  const void* W2   = d_in[5];
  const void* b2   = d_in[6];
  const void* fcW  = d_in[7];
  const void* fcb  = d_in[8];

  const int N = in_sizes[0] / 64;       // 50000 (packing requires N <= 65536)
  const int E = in_sizes[1] / 2;        // 800000
  const int NOUT = in_sizes[8];         // 1
  const int G = out_size / NOUT;        // 128
  const int nbuckets = (N + 63) >> 6;   // 782

  size_t off = 0;
  auto alloc = [&](size_t bytes) -> char* {
    char* p = (char*)d_ws + off;
    off += (bytes + 511) & ~(size_t)511;
    return p;
  };
  int*   flags   = (int*)  alloc(512);
  size_t z0 = off;                                  // ---- zero-region start ----
  int*   done    = (int*)  alloc(512);
  int*   gcursor = (int*)  alloc((size_t)nbuckets*4);
  float* S       = (float*)alloc((size_t)G*NOUT*4);
  size_t z1 = off;                                  // ---- zero-region end ----
  float* dinv    = (float*)alloc((size_t)N*4);
  int*   beg     = (int*)  alloc((size_t)N*4);
  int*   endv    = (int*)  alloc((size_t)N*4);
  unsigned int*   log  = (unsigned int*)  alloc((size_t)nbuckets*CAP*4);  // 12.8 MB
  unsigned short* csr  = (unsigned short*)alloc((size_t)nbuckets*CAP*2);  // 6.4 MB
  unsigned short* yB   = (unsigned short*)alloc((size_t)N*64*2);          // 6.4 MB  y = x@W1 (bf16)
  unsigned short* g1   = (unsigned short*)alloc((size_t)N*64*2);          // 6.4 MB  g1 = relu(...)*dinv (bf16)
  unsigned int*   aBuf = (unsigned int*)  alloc((size_t)N*32*4);          // 6.4 MB  a2 (bf16)
  (void)ws_size; (void)n_in;

  int nLog = (E + LB_EDGES - 1) / LB_EDGES;          // 98
  int nGem = (N + 63) / 64;                          // 782 (64-row tiles)

  hipMemsetAsync((char*)d_ws + z0, 0, z1 - z0, stream);   // done + gcursor + S

  k_pre     <<<nLog + nGem,   512, 0, stream>>>(ei, E, N, flags, gcursor, log, nbuckets,
                                                x, W1, yB, nLog);
  k_bsort   <<<nbuckets,      512, 0, stream>>>(log, gcursor, csr, beg, endv, dinv, N);

  k_agg     <<<(N+3)/4,       256, 0, stream>>>(yB, csr, beg, endv, dinv, b1, flags, 1,
                                                (uint4*)g1, N);                        // g1 (bf16)
  k_agg     <<<(N+3)/4,       256, 0, stream>>>(g1, csr, beg, endv, dinv, b1, flags, 0,
                                                (uint4*)aBuf, N);                      // a2 (bf16)
  k_gemm2pool<<<(N+127)/128,  512, 0, stream>>>((const unsigned int*)aBuf, W2, b2, fcW, batch, flags,
                                                S, done, fcb, d_out, N, G, NOUT);
}

// Round 15
// 177.394 us; speedup vs baseline: 1.3979x; 1.3979x over previous
//
#include <hip/hip_runtime.h>
#include <hip/hip_bf16.h>

typedef __hip_bfloat16 bf16;

// flags[0] = 1 if floats are f32 (else bf16); flags[1] = 1 if ints are int64 (else int32)
static __device__ __forceinline__ float loadF(const void* p, long long i, int f32){
  return f32 ? ((const float*)p)[i] : __bfloat162float(((const bf16*)p)[i]);
}
static __device__ __forceinline__ int loadI(const void* p, long long i, int i64){
  return i64 ? (int)((const long long*)p)[i] : ((const int*)p)[i];
}
// round-to-nearest-even float -> bf16 bits (finite inputs)
static __device__ __forceinline__ unsigned short f2bf(float f){
  unsigned u = __float_as_uint(f);
  return (unsigned short)((u + 0x7FFFu + ((u>>16)&1u)) >> 16);
}
static __device__ __forceinline__ float bf2f(unsigned v){
  return __uint_as_float(v<<16);
}

#define CAP 4096        // log entries per bucket (avg ~1023)
#define LB_EDGES 8192   // edges per logbuild block (98 blocks; 32KB stash)

// ---------------- fused pre-pass (512 threads): bucket-log build || y = x @ W1 ----------------
// Per-block dtype sniff; block 0 publishes flags for downstream kernels.
// blocks [0, nLog) build the packed edge log; blocks [nLog, ...) compute y (128x64, acc[4][4]).
__global__ __launch_bounds__(512) void k_pre(const void* __restrict__ ei, int E, int N,
                                             int* __restrict__ flags,
                                             int* __restrict__ gcursor,
                                             unsigned int* __restrict__ log, int nbuckets,
                                             const void* __restrict__ x, const void* __restrict__ W,
                                             unsigned short* __restrict__ y, int nLog){
  __shared__ unsigned int smem[12416];   // 49664 B: max(log role 40 KB, gemm role 48.5 KB)
  __shared__ int sflag[2];
  int t = threadIdx.x;
  // ---- per-block dtype sniff (L2-broadcast reads, ~2KB shared by all blocks) ----
  if(t == 0){ sflag[0] = 0; sflag[1] = 0; }
  __syncthreads();
  {
    const unsigned int* xw  = (const unsigned int*)x;
    const unsigned int* eiw = (const unsigned int*)ei;
    if(t < 256){
      unsigned w = xw[t];
      int e = (int)((w>>7)&0xFFu);
      if(e>=110 && e<=135) atomicAdd(&sflag[0], 1);      // bf16-pair exponent signature
    } else {
      int i = t - 256;
      if(eiw[2*i+1] != 0u) atomicAdd(&sflag[1], 1);      // int64 high words
    }
  }
  __syncthreads();
  int f32 = (sflag[0] < 128) ? 1 : 0;
  int i64 = (sflag[1] < 128) ? 1 : 0;
  if(blockIdx.x == 0 && t == 0){ flags[0] = f32; flags[1] = i64; }  // for later kernels
  if((int)blockIdx.x < nLog){
    // ---- logbuild role: packed (dst<<16)|src, grouped by dst>>6 ----
    unsigned int* stash = smem;                       // [0, 8192): 32 KB
    int* hcnt  = (int*)(smem + LB_EDGES);             // [8192, 9216): 4 KB
    int* hbase = (int*)(smem + LB_EDGES + 1024);      // [9216, 10240): 4 KB
    for(int b=t; b<nbuckets; b+=512) hcnt[b] = 0;
    __syncthreads();
    long long e0 = (long long)blockIdx.x*LB_EDGES;
    int cnt = (int)(((long long)E - e0) < LB_EDGES ? ((long long)E - e0) : LB_EDGES);
    for(int k=t; k<cnt; k+=512){
      long long e = e0 + k;
      int s = loadI(ei, e, i64);                 s = min(max(s,0), N-1);
      int d = loadI(ei, (long long)E + e, i64);  d = min(max(d,0), N-1);
      unsigned p = (((unsigned)d)<<16) | (unsigned)s;   // requires N <= 65536
      stash[k] = p;
      atomicAdd(&hcnt[d>>6], 1);
    }
    __syncthreads();
    for(int b=t; b<nbuckets; b+=512){
      int c = hcnt[b];
      hbase[b] = (c>0) ? atomicAdd(&gcursor[b], c) : 0;
      hcnt[b] = 0;
    }
    __syncthreads();
    for(int k=t; k<cnt; k+=512){
      unsigned p = stash[k];
      int b = (int)(p>>22);                      // dst>>6
      int pos = hbase[b] + atomicAdd(&hcnt[b], 1);
      if(pos < CAP) log[(long long)b*CAP + pos] = p;
    }
  } else {
    // ---- gemm role: y = x @ W1, 128 rows x 64 cols per block, 4 rows x 4 cols/thread ----
    float* Ws = (float*)smem;                    // [0, 4096): 16 KB
    float* xs = (float*)(smem + 4096);           // 128*65 floats = 33280 B
    int row0 = ((int)blockIdx.x - nLog)*128;
    if(f32){
      const float4* W4 = (const float4*)W;
      for(int i=t;i<1024;i+=512){
        float4 v = W4[i];
        Ws[i*4]=v.x; Ws[i*4+1]=v.y; Ws[i*4+2]=v.z; Ws[i*4+3]=v.w;
      }
      const float4* X4 = (const float4*)x;
      for(int i=t;i<2048;i+=512){
        int r = i>>4, c4 = i&15;
        int gr = row0 + r;
        float4 v = {0.f,0.f,0.f,0.f};
        if(gr<N) v = X4[(long long)gr*16 + c4];
        float* xd = &xs[r*65 + c4*4];
        xd[0]=v.x; xd[1]=v.y; xd[2]=v.z; xd[3]=v.w;
      }
    } else {
      for(int i=t;i<4096;i+=512) Ws[i] = loadF(W, i, 0);
      const unsigned int* X32 = (const unsigned int*)x;
      for(int i=t;i<4096;i+=512){
        int r = i>>5, kd = i&31;
        int gr = row0 + r;
        unsigned v = (gr<N) ? X32[(long long)gr*32 + kd] : 0u;
        xs[r*65 + 2*kd    ] = bf2f(v & 0xFFFFu);
        xs[r*65 + 2*kd + 1] = bf2f(v >> 16);
      }
    }
    __syncthreads();
    int cg = t&15, rg = t>>4;                    // rg in [0,32): 4 rows each
    int col_g = cg*4, row_g = rg*4;
    float acc[4][4];
    #pragma unroll
    for(int r=0;r<4;r++){ acc[r][0]=0.f; acc[r][1]=0.f; acc[r][2]=0.f; acc[r][3]=0.f; }
    for(int k=0;k<64;k++){
      float4 w = *(const float4*)&Ws[k*64 + col_g];
      float xr[4];
      #pragma unroll
      for(int r=0;r<4;r++) xr[r] = xs[(row_g+r)*65 + k];
      #pragma unroll
      for(int r=0;r<4;r++){
        acc[r][0] += xr[r]*w.x; acc[r][1] += xr[r]*w.y;
        acc[r][2] += xr[r]*w.z; acc[r][3] += xr[r]*w.w;
      }
    }
    #pragma unroll
    for(int r=0;r<4;r++){
      int gr = row0 + row_g + r;
      if(gr<N){
        ushort4 st;
        st.x = f2bf(acc[r][0]); st.y = f2bf(acc[r][1]);
        st.z = f2bf(acc[r][2]); st.w = f2bf(acc[r][3]);
        *(ushort4*)&y[(long long)gr*64 + col_g] = st;
      }
    }
  }
}

// ---------------- per-bucket counting sort + dinv (512 threads) ----------------
__global__ __launch_bounds__(512) void k_bsort(const unsigned int* __restrict__ log,
                                               const int* __restrict__ gcursor,
                                               unsigned short* __restrict__ csr,
                                               int* __restrict__ beg, int* __restrict__ endv,
                                               float* __restrict__ dinv, int N){
  __shared__ int hist[64];
  __shared__ int cur[64];
  int b = blockIdx.x, t = threadIdx.x;
  if(t < 64) hist[t] = 0;
  __syncthreads();
  int n = min(gcursor[b], CAP);
  const unsigned int* L = log + (long long)b*CAP;
  for(int j=t; j<n; j+=512) atomicAdd(&hist[(L[j]>>16)&63], 1);
  __syncthreads();
  if(t < 64){                                   // wave 0: exclusive scan over 64 bins
    int v = hist[t];
    int inc = v;
    #pragma unroll
    for(int o=1; o<64; o<<=1){
      int u = __shfl_up(inc, o);
      if(t >= o) inc += u;
    }
    int excl = inc - v;
    cur[t] = excl;
    int node = b*64 + t;
    if(node < N){
      int base = b*CAP + excl;
      beg[node]  = base;
      endv[node] = base + v;
      dinv[node] = rsqrtf((float)(v + 1));      // +1 = self loop
    }
  }
  __syncthreads();
  unsigned short* C = csr + (long long)b*CAP;
  for(int j=t; j<n; j+=512){
    unsigned p = L[j];
    int l = (int)((p>>16)&63u);
    int pos = atomicAdd(&cur[l], 1);
    C[pos] = (unsigned short)(p & 0xFFFFu);
  }
}

// ---------------- AGG: wave per node, uint4 row-segment gather ----------------
// lane = (eg = lane>>3 edge slot, q = lane&7 feat segment); one vector instr = 8 rows.
// Self-row + dinv issued BEFORE the gather loop so their latency hides under it.
// mode=1: input is y (unscaled) -> rows scaled by dinv[s], self by dv;
//         out = bf16( relu( dv*(sum dinv_s*y_s + dv*y_d) + bias ) * dv )   [pre-scaled for next hop]
// mode=0: input pre-scaled -> out = bf16( dv*(sum g_s + g_d) )
__global__ __launch_bounds__(256) void k_agg(const unsigned short* __restrict__ g,
                                             const unsigned short* __restrict__ csr,
                                             const int* __restrict__ beg, const int* __restrict__ endv,
                                             const float* __restrict__ dinv,
                                             const void* __restrict__ bias, const int* __restrict__ flags,
                                             int mode,
                                             uint4* __restrict__ out128, int N){
  int node = blockIdx.x*4 + (threadIdx.x>>6);
  int lane = threadIdx.x&63;
  if(node >= N) return;
  int q = lane&7, eg = lane>>3;
  const uint4* G128 = (const uint4*)g;          // row = 8 uint4 (64 bf16)
  // issue self row + dinv EARLY — overlaps the whole gather phase
  uint4 sv = {0u,0u,0u,0u};
  float dv = 0.f;
  if(eg == 0){
    sv = G128[(long long)node*8 + q];
    dv = dinv[node];
  }
  int j = beg[node], e = endv[node];
  float a0=0.f,a1=0.f,a2=0.f,a3=0.f,a4=0.f,a5=0.f,a6=0.f,a7=0.f;
  if(mode){                                     // gather with per-edge dinv[s] scale
    for(; j+16<=e; j+=16){
      int sA = csr[j + eg];
      int sB = csr[j + 8 + eg];
      float dA = dinv[sA], dB = dinv[sB];
      uint4 vA = G128[(long long)sA*8 + q];
      uint4 vB = G128[(long long)sB*8 + q];
      a0 += dA*bf2f(vA.x & 0xFFFFu); a1 += dA*bf2f(vA.x >> 16);
      a2 += dA*bf2f(vA.y & 0xFFFFu); a3 += dA*bf2f(vA.y >> 16);
      a4 += dA*bf2f(vA.z & 0xFFFFu); a5 += dA*bf2f(vA.z >> 16);
      a6 += dA*bf2f(vA.w & 0xFFFFu); a7 += dA*bf2f(vA.w >> 16);
      a0 += dB*bf2f(vB.x & 0xFFFFu); a1 += dB*bf2f(vB.x >> 16);
      a2 += dB*bf2f(vB.y & 0xFFFFu); a3 += dB*bf2f(vB.y >> 16);
      a4 += dB*bf2f(vB.z & 0xFFFFu); a5 += dB*bf2f(vB.z >> 16);
      a6 += dB*bf2f(vB.w & 0xFFFFu); a7 += dB*bf2f(vB.w >> 16);
    }
    for(; j+8<=e; j+=8){
      int s = csr[j + eg];
      float d = dinv[s];
      uint4 v = G128[(long long)s*8 + q];
      a0 += d*bf2f(v.x & 0xFFFFu); a1 += d*bf2f(v.x >> 16);
      a2 += d*bf2f(v.y & 0xFFFFu); a3 += d*bf2f(v.y >> 16);
      a4 += d*bf2f(v.z & 0xFFFFu); a5 += d*bf2f(v.z >> 16);
      a6 += d*bf2f(v.w & 0xFFFFu); a7 += d*bf2f(v.w >> 16);
    }
    if(j + eg < e){
      int s = csr[j + eg];
      float d = dinv[s];
      uint4 v = G128[(long long)s*8 + q];
      a0 += d*bf2f(v.x & 0xFFFFu); a1 += d*bf2f(v.x >> 16);
      a2 += d*bf2f(v.y & 0xFFFFu); a3 += d*bf2f(v.y >> 16);
      a4 += d*bf2f(v.z & 0xFFFFu); a5 += d*bf2f(v.z >> 16);
      a6 += d*bf2f(v.w & 0xFFFFu); a7 += d*bf2f(v.w >> 16);
    }
  } else {
    for(; j+16<=e; j+=16){
      int sA = csr[j + eg];
      int sB = csr[j + 8 + eg];
      uint4 vA = G128[(long long)sA*8 + q];
      uint4 vB = G128[(long long)sB*8 + q];
      a0 += bf2f(vA.x & 0xFFFFu); a1 += bf2f(vA.x >> 16);
      a2 += bf2f(vA.y & 0xFFFFu); a3 += bf2f(vA.y >> 16);
      a4 += bf2f(vA.z & 0xFFFFu); a5 += bf2f(vA.z >> 16);
      a6 += bf2f(vA.w & 0xFFFFu); a7 += bf2f(vA.w >> 16);
      a0 += bf2f(vB.x & 0xFFFFu); a1 += bf2f(vB.x >> 16);
      a2 += bf2f(vB.y & 0xFFFFu); a3 += bf2f(vB.y >> 16);
      a4 += bf2f(vB.z & 0xFFFFu); a5 += bf2f(vB.z >> 16);
      a6 += bf2f(vB.w & 0xFFFFu); a7 += bf2f(vB.w >> 16);
    }
    for(; j+8<=e; j+=8){
      int s = csr[j + eg];
      uint4 v = G128[(long long)s*8 + q];
      a0 += bf2f(v.x & 0xFFFFu); a1 += bf2f(v.x >> 16);
      a2 += bf2f(v.y & 0xFFFFu); a3 += bf2f(v.y >> 16);
      a4 += bf2f(v.z & 0xFFFFu); a5 += bf2f(v.z >> 16);
      a6 += bf2f(v.w & 0xFFFFu); a7 += bf2f(v.w >> 16);
    }
    if(j + eg < e){
      int s = csr[j + eg];
      uint4 v = G128[(long long)s*8 + q];
      a0 += bf2f(v.x & 0xFFFFu); a1 += bf2f(v.x >> 16);
      a2 += bf2f(v.y & 0xFFFFu); a3 += bf2f(v.y >> 16);
      a4 += bf2f(v.z & 0xFFFFu); a5 += bf2f(v.z >> 16);
      a6 += bf2f(v.w & 0xFFFFu); a7 += bf2f(v.w >> 16);
    }
  }
  #pragma unroll
  for(int m=8; m<64; m<<=1){                    // combine 8 edge slots
    a0 += __shfl_xor(a0, m, 64); a1 += __shfl_xor(a1, m, 64);
    a2 += __shfl_xor(a2, m, 64); a3 += __shfl_xor(a3, m, 64);
    a4 += __shfl_xor(a4, m, 64); a5 += __shfl_xor(a5, m, 64);
    a6 += __shfl_xor(a6, m, 64); a7 += __shfl_xor(a7, m, 64);
  }
  if(eg == 0){
    float selfs = mode ? dv : 1.f;              // mode1: self term is dv*y_d
    float f0 = (a0 + selfs*bf2f(sv.x & 0xFFFFu)) * dv;
    float f1 = (a1 + selfs*bf2f(sv.x >> 16)) * dv;
    float f2 = (a2 + selfs*bf2f(sv.y & 0xFFFFu)) * dv;
    float f3 = (a3 + selfs*bf2f(sv.y >> 16)) * dv;
    float f4 = (a4 + selfs*bf2f(sv.z & 0xFFFFu)) * dv;
    float f5 = (a5 + selfs*bf2f(sv.z >> 16)) * dv;
    float f6 = (a6 + selfs*bf2f(sv.w & 0xFFFFu)) * dv;
    float f7 = (a7 + selfs*bf2f(sv.w >> 16)) * dv;
    if(mode){                                   // layer-1 epilogue: relu(S+b1)*dinv
      int f32 = flags[0];
      f0 = fmaxf(f0 + loadF(bias, q*8+0, f32), 0.f) * dv;
      f1 = fmaxf(f1 + loadF(bias, q*8+1, f32), 0.f) * dv;
      f2 = fmaxf(f2 + loadF(bias, q*8+2, f32), 0.f) * dv;
      f3 = fmaxf(f3 + loadF(bias, q*8+3, f32), 0.f) * dv;
      f4 = fmaxf(f4 + loadF(bias, q*8+4, f32), 0.f) * dv;
      f5 = fmaxf(f5 + loadF(bias, q*8+5, f32), 0.f) * dv;
      f6 = fmaxf(f6 + loadF(bias, q*8+6, f32), 0.f) * dv;
      f7 = fmaxf(f7 + loadF(bias, q*8+7, f32), 0.f) * dv;
    }
    uint4 o;
    o.x = (unsigned)f2bf(f0) | ((unsigned)f2bf(f1) << 16);
    o.y = (unsigned)f2bf(f2) | ((unsigned)f2bf(f3) << 16);
    o.z = (unsigned)f2bf(f4) | ((unsigned)f2bf(f5) << 16);
    o.w = (unsigned)f2bf(f6) | ((unsigned)f2bf(f7) << 16);
    out128[(long long)node*8 + q] = o;
  }
}

// ---------------- fused GEMM2 + relu + fcW-dot + mean-pool + (last block) final ----------------
// 512 threads (8 waves): thread covers 4 rows x 8 cols of the 128x128 tile.
static __device__ __forceinline__ int lower_bound_batch(const void* batch, int N, int key, int i64){
  int lo = 0, hi = N;
  while(lo < hi){ int mid = (lo+hi)>>1; if(loadI(batch, mid, i64) < key) lo = mid+1; else hi = mid; }
  return lo;
}

__global__ __launch_bounds__(512) void k_gemm2pool(const unsigned int* __restrict__ A32, const void* __restrict__ W,
                                                   const void* __restrict__ b, const void* __restrict__ fcW,
                                                   const void* __restrict__ batch, const int* __restrict__ flags,
                                                   float* __restrict__ S, int* __restrict__ done,
                                                   const void* __restrict__ fcb, void* __restrict__ out,
                                                   int N, int G, int NOUT){
  __shared__ float Ws[64*128];     // 32 KB
  __shared__ float xs[128*65];     // 32.5 KB
  __shared__ float Sloc[128*4];
  __shared__ int gid[128];
  __shared__ int lastBlk;
  int f32 = flags[0], i64 = flags[1];
  int tid = threadIdx.x;
  int row0 = blockIdx.x*128;
  if(f32){
    const float4* W4 = (const float4*)W;
    for(int i=tid;i<2048;i+=512){
      float4 v = W4[i];
      Ws[i*4]=v.x; Ws[i*4+1]=v.y; Ws[i*4+2]=v.z; Ws[i*4+3]=v.w;
    }
  } else {
    for(int i=tid;i<8192;i+=512) Ws[i] = loadF(W, i, 0);
  }
  for(int i=tid;i<4096;i+=512){                 // 4096 dwords = 128 rows x 32 dwords
    int r = i>>5, kd = i&31;
    int gr = row0 + r;
    unsigned v = (gr<N) ? A32[(long long)gr*32 + kd] : 0u;
    xs[r*65 + 2*kd    ] = bf2f(v & 0xFFFFu);
    xs[r*65 + 2*kd + 1] = bf2f(v >> 16);
  }
  if(tid < 128){
    int node = row0 + tid;
    gid[tid] = (node < N) ? loadI(batch, node, i64) : 0;
  }
  if(tid < 512) Sloc[tid] = 0.f;
  __syncthreads();
  int cg = tid&15, rg = tid>>4;                 // rg in [0,32): 4 rows each
  int c0 = cg*4, c1 = 64 + cg*4, row_g = rg*4;
  float acc[4][8];
  #pragma unroll
  for(int r=0;r<4;r++)
    #pragma unroll
    for(int c=0;c<8;c++) acc[r][c]=0.f;
  for(int k=0;k<64;k++){
    float4 w0 = *(const float4*)&Ws[k*128 + c0];
    float4 w1 = *(const float4*)&Ws[k*128 + c1];
    float xr[4];
    #pragma unroll
    for(int r=0;r<4;r++) xr[r] = xs[(row_g+r)*65 + k];
    #pragma unroll
    for(int r=0;r<4;r++){
      acc[r][0] += xr[r]*w0.x; acc[r][1] += xr[r]*w0.y;
      acc[r][2] += xr[r]*w0.z; acc[r][3] += xr[r]*w0.w;
      acc[r][4] += xr[r]*w1.x; acc[r][5] += xr[r]*w1.y;
      acc[r][6] += xr[r]*w1.z; acc[r][7] += xr[r]*w1.w;
    }
  }
  // bias + relu in registers
  #pragma unroll
  for(int c=0;c<8;c++){
    int col = (c<4) ? (c0+c) : (c1+c-4);
    float bb = loadF(b, col, f32);
    #pragma unroll
    for(int r=0;r<4;r++){ float z = acc[r][c]+bb; acc[r][c] = z>0.f?z:0.f; }
  }
  // fcW dot + pooled partial sums
  int nv = N - row0; nv = nv < 128 ? nv : 128;
  if(nv > 0){
    int gmin = gid[0], gmax = gid[nv-1];
    bool ldsOK = (NOUT <= 4) && (gmax - gmin < 128);
    for(int o=0;o<NOUT;o++){
      float fw[8];
      #pragma unroll
      for(int c=0;c<8;c++){
        int col = (c<4) ? (c0+c) : (c1+c-4);
        fw[c] = loadF(fcW, (long long)col*NOUT + o, f32);
      }
      #pragma unroll
      for(int r=0;r<4;r++){
        float z = acc[r][0]*fw[0] + acc[r][1]*fw[1] + acc[r][2]*fw[2] + acc[r][3]*fw[3]
                + acc[r][4]*fw[4] + acc[r][5]*fw[5] + acc[r][6]*fw[6] + acc[r][7]*fw[7];
        #pragma unroll
        for(int m=1;m<16;m<<=1) z += __shfl_xor(z, m, 64);
        int nl = row_g + r;
        if(cg==0 && nl < nv){
          int gg = gid[nl];
          if(ldsOK) atomicAdd(&Sloc[(gg-gmin)*NOUT + o], z);
          else      atomicAdd(&S[(long long)gg*NOUT + o], z);
        }
      }
    }
    if(ldsOK){
      __syncthreads();
      int nbin = (gmax - gmin + 1)*NOUT;
      for(int i=tid; i<nbin; i+=512){
        float v = Sloc[i];
        if(v != 0.f){
          int bin = i / NOUT, o = i - bin*NOUT;
          atomicAdd(&S[(long long)(gmin+bin)*NOUT + o], v);
        }
      }
    }
  }
  // last-block final: out[g,o] = S[g,o]/count_g + fcb[o].
  // All S updates are DEVICE-SCOPE atomicAdds (performed at the coherence point),
  // so no cache writeback is needed — only completion before done++ is observed.
  asm volatile("s_waitcnt vmcnt(0)" ::: "memory");
  if(tid==0) lastBlk = (atomicAdd(done, 1) == (int)gridDim.x - 1) ? 1 : 0;
  __syncthreads();
  if(lastBlk){
    for(int g2=tid; g2<G; g2+=512){
      int c = lower_bound_batch(batch, N, g2+1, i64) - lower_bound_batch(batch, N, g2, i64);
      float inv = 1.f / (float)(c > 0 ? c : 1);
      for(int o=0;o<NOUT;o++){
        float sv = atomicAdd(&S[(long long)g2*NOUT + o], 0.f);   // coherent device-scope read
        float r = sv*inv + loadF(fcb, o, f32);
        if(f32) ((float*)out)[g2*NOUT+o] = r;
        else    ((unsigned short*)out)[g2*NOUT+o] = f2bf(r);
      }
    }
  }
}

extern "C" void kernel_launch(void* const* d_in, const int* in_sizes, int n_in,
                              void* d_out, int out_size, void* d_ws, size_t ws_size,
                              hipStream_t stream) {
  const void* x    = d_in[0];
  const void* ei   = d_in[1];
  const void* batch= d_in[2];
  const void* W1   = d_in[3];
  const void* b1   = d_in[4];
  const void* W2   = d_in[5];
  const void* b2   = d_in[6];
  const void* fcW  = d_in[7];
  const void* fcb  = d_in[8];

  const int N = in_sizes[0] / 64;       // 50000 (packing requires N <= 65536)
  const int E = in_sizes[1] / 2;        // 800000
  const int NOUT = in_sizes[8];         // 1
  const int G = out_size / NOUT;        // 128
  const int nbuckets = (N + 63) >> 6;   // 782

  size_t off = 0;
  auto alloc = [&](size_t bytes) -> char* {
    char* p = (char*)d_ws + off;
    off += (bytes + 511) & ~(size_t)511;
    return p;
  };
  int*   flags   = (int*)  alloc(512);
  size_t z0 = off;                                  // ---- zero-region start ----
  int*   done    = (int*)  alloc(512);
  int*   gcursor = (int*)  alloc((size_t)nbuckets*4);
  float* S       = (float*)alloc((size_t)G*NOUT*4);
  size_t z1 = off;                                  // ---- zero-region end ----
  float* dinv    = (float*)alloc((size_t)N*4);
  int*   beg     = (int*)  alloc((size_t)N*4);
  int*   endv    = (int*)  alloc((size_t)N*4);
  unsigned int*   log  = (unsigned int*)  alloc((size_t)nbuckets*CAP*4);  // 12.8 MB
  unsigned short* csr  = (unsigned short*)alloc((size_t)nbuckets*CAP*2);  // 6.4 MB
  unsigned short* yB   = (unsigned short*)alloc((size_t)N*64*2);          // 6.4 MB  y = x@W1 (bf16)
  unsigned short* g1   = (unsigned short*)alloc((size_t)N*64*2);          // 6.4 MB  g1 = relu(...)*dinv (bf16)
  unsigned int*   aBuf = (unsigned int*)  alloc((size_t)N*32*4);          // 6.4 MB  a2 (bf16)
  (void)ws_size; (void)n_in;

  int nLog = (E + LB_EDGES - 1) / LB_EDGES;          // 98
  int nGem = (N + 127) / 128;                        // 391 (128-row tiles)

  hipMemsetAsync((char*)d_ws + z0, 0, z1 - z0, stream);   // done + gcursor + S

  k_pre     <<<nLog + nGem,   512, 0, stream>>>(ei, E, N, flags, gcursor, log, nbuckets,
                                                x, W1, yB, nLog);
  k_bsort   <<<nbuckets,      512, 0, stream>>>(log, gcursor, csr, beg, endv, dinv, N);

  k_agg     <<<(N+3)/4,       256, 0, stream>>>(yB, csr, beg, endv, dinv, b1, flags, 1,
                                                (uint4*)g1, N);                        // g1 (bf16)
  k_agg     <<<(N+3)/4,       256, 0, stream>>>(g1, csr, beg, endv, dinv, b1, flags, 0,
                                                (uint4*)aBuf, N);                      // a2 (bf16)
  k_gemm2pool<<<(N+127)/128,  512, 0, stream>>>((const unsigned int*)aBuf, W2, b2, fcW, batch, flags,
                                                S, done, fcb, d_out, N, G, NOUT);
}